// Round 1
// baseline (526.862 us; speedup 1.0000x reference)
//
#include <hip/hip_runtime.h>
#include <hip/hip_bf16.h>
#include <stdint.h>

// MPO linear: out = x @ W^T + bias, W[m1*64+m2, n1*64+n2] = sum_r c1[m1,n1,r] c2[r,m2,n2]
// R4: replace main GEMM with 256x256 8-phase deep-pipelined schedule (T2+T3+T4+T5):
//     - BK=64 split into two contiguous k-half sub-buffers (16KB each) so counted
//       vmcnt(4) is provably safe with double buffering (ledger in comments below).
//     - per phase: ds_read subtile + 1 sub-buffer gl2lds prefetch + raw s_barrier +
//       setprio(1) around 16 MFMA. vmcnt NEVER drains to 0 in the main loop.
//     - chunk-XOR swizzle (c ^ (row&3) ^ ((row>>2)&3)) on 64B rows -> 2-way max
//       bank aliasing (free). Source-side pre-swizzle, linear gl2lds dest (rule 21).
//     - XCD-bijective block swizzle (512 blocks, 64/XCD chunk -> A-panel L2 reuse).
//     W-GEMM keeps the R1-proven 128^2 BK=32 structure (K=256, ~30us, low upside).

#define TOKENS 8192
#define DIN    4096
#define DOUT   4096
#define RANK   256
#define GEMM_K 4096

typedef __attribute__((ext_vector_type(8))) short   short8;
typedef __attribute__((ext_vector_type(4))) float   floatx4;

__device__ __forceinline__ unsigned short f2bf(float f) {
  union { float f; unsigned u; } v; v.f = f;
  unsigned r = v.u + 0x7FFFu + ((v.u >> 16) & 1u);  // round-to-nearest-even
  return (unsigned short)(r >> 16);
}

__device__ __forceinline__ void gl2lds16(const void* g, void* l) {
  __builtin_amdgcn_global_load_lds(
      (const __attribute__((address_space(1))) unsigned int*)g,
      (__attribute__((address_space(3))) unsigned int*)l,
      16, 0, 0);
}

// ---- fp32 -> bf16 convert, n multiple of 2048 ----
__global__ __launch_bounds__(256) void k_f32_to_bf16(const float* __restrict__ src,
                                                     unsigned short* __restrict__ dst,
                                                     int n) {
  int i = (blockIdx.x * 256 + threadIdx.x) * 8;
  if (i >= n) return;
  float4 a = *(const float4*)(src + i);
  float4 b = *(const float4*)(src + i + 4);
  short8 o;
  o[0] = (short)f2bf(a.x); o[1] = (short)f2bf(a.y);
  o[2] = (short)f2bf(a.z); o[3] = (short)f2bf(a.w);
  o[4] = (short)f2bf(b.x); o[5] = (short)f2bf(b.y);
  o[6] = (short)f2bf(b.z); o[7] = (short)f2bf(b.w);
  *(short8*)(dst + i) = o;
}

// ---- core2 [256][4096] f32  ->  c2t [4096][256] bf16 (LDS tile transpose) ----
__global__ __launch_bounds__(256) void k_transpose_c2(const float* __restrict__ c2,
                                                      unsigned short* __restrict__ c2t) {
  __shared__ float tile[64][65];
  const int p0 = blockIdx.x * 64;
  const int r0 = blockIdx.y * 64;
  {
    const int px = threadIdx.x & 63;
    const int rb = threadIdx.x >> 6;           // 0..3
    for (int s = 0; s < 16; ++s) {
      int r = rb + s * 4;
      tile[r][px] = c2[(size_t)(r0 + r) * 4096 + p0 + px];
    }
  }
  __syncthreads();
  {
    const int rx = threadIdx.x & 63;
    const int pb = threadIdx.x >> 6;
    for (int s = 0; s < 16; ++s) {
      int p = pb + s * 4;
      c2t[(size_t)(p0 + p) * 256 + r0 + rx] = f2bf(tile[rx][p]);
    }
  }
}

// ---- R1-proven 128x128 BK=32 GEMM (kept for the small W-GEMM, K=256) ----
// C = A @ B^T. PERM=true: permuted bf16 store of W.
template <int K, int BK, bool PERM>
__global__ __launch_bounds__(256) void k_gemm_bt(const unsigned short* __restrict__ A,
                                                 const unsigned short* __restrict__ B,
                                                 float* __restrict__ outF,
                                                 unsigned short* __restrict__ outW,
                                                 const float* __restrict__ bias) {
  constexpr int ROWB   = BK * 2;
  constexpr int CM     = BK / 8 - 1;
  constexpr int ROUNDS = BK / 16;
  constexpr int KK     = BK / 32;

  __shared__ __align__(16) unsigned short As[128 * BK];
  __shared__ __align__(16) unsigned short Bs[128 * BK];

  const int tid  = threadIdx.x;
  const int lane = tid & 63;
  const int wave = tid >> 6;
  const int m0 = blockIdx.y * 128;
  const int n0 = blockIdx.x * 128;

  const int waveM = (wave & 1) * 64;
  const int waveN = (wave >> 1) * 64;
  const int l15  = lane & 15;
  const int quad = lane >> 4;

  floatx4 acc[4][4];
#pragma unroll
  for (int i = 0; i < 4; ++i)
#pragma unroll
    for (int j = 0; j < 4; ++j) acc[i][j] = (floatx4)0.0f;

  const size_t rowBytes = (size_t)K * 2;

  for (int kt = 0; kt < K; kt += BK) {
    __syncthreads();
#pragma unroll
    for (int j = 0; j < ROUNDS; ++j) {
      const int flat = (j * 4 + wave) * 1024 + lane * 16;
      const int row  = flat / ROWB;
      const int c    = (flat >> 4) & CM;
      const int cs   = c ^ (row & CM);
      const int ldsb = (j * 4 + wave) * 1024;
      gl2lds16((const char*)A + (size_t)(m0 + row) * rowBytes + (size_t)kt * 2 + cs * 16,
               (char*)As + ldsb);
      gl2lds16((const char*)B + (size_t)(n0 + row) * rowBytes + (size_t)kt * 2 + cs * 16,
               (char*)Bs + ldsb);
    }
    __syncthreads();

#pragma unroll
    for (int kk = 0; kk < KK; ++kk) {
      short8 af[4], bfr[4];
#pragma unroll
      for (int mi = 0; mi < 4; ++mi) {
        const int row = waveM + mi * 16 + l15;
        const int cs  = (kk * 4 + quad) ^ (row & CM);
        af[mi] = *(const short8*)(As + row * BK + cs * 8);
      }
#pragma unroll
      for (int ni = 0; ni < 4; ++ni) {
        const int row = waveN + ni * 16 + l15;
        const int cs  = (kk * 4 + quad) ^ (row & CM);
        bfr[ni] = *(const short8*)(Bs + row * BK + cs * 8);
      }
#pragma unroll
      for (int mi = 0; mi < 4; ++mi)
#pragma unroll
        for (int ni = 0; ni < 4; ++ni)
          acc[mi][ni] = __builtin_amdgcn_mfma_f32_16x16x32_bf16(af[mi], bfr[ni], acc[mi][ni], 0, 0, 0);
    }
  }

  if (!PERM) {
#pragma unroll
    for (int ni = 0; ni < 4; ++ni) {
      const int col = n0 + waveN + ni * 16 + l15;
      const float bv = bias[col];
#pragma unroll
      for (int mi = 0; mi < 4; ++mi) {
        const int rowb = m0 + waveM + mi * 16 + quad * 4;
#pragma unroll
        for (int r = 0; r < 4; ++r)
          outF[(size_t)(rowb + r) * DOUT + col] = acc[mi][ni][r] + bv;
      }
    }
  } else {
#pragma unroll
    for (int ni = 0; ni < 4; ++ni) {
      const int bcol = n0 + waveN + ni * 16 + l15;
      const int m2 = bcol >> 6, n2 = bcol & 63;
#pragma unroll
      for (int mi = 0; mi < 4; ++mi) {
        const int arow0 = m0 + waveM + mi * 16 + quad * 4;
#pragma unroll
        for (int r = 0; r < 4; ++r) {
          const int arow = arow0 + r;
          const int m1 = arow >> 6, n1 = arow & 63;
          outW[(size_t)(m1 * 64 + m2) * 4096 + (n1 * 64 + n2)] = f2bf(acc[mi][ni][r]);
        }
      }
    }
  }
}

// ---- R4: 256x256 8-phase deep-pipelined bf16 GEMM, C = A @ B^T + bias ----
// A:[8192][4096], B:[4096][4096] bf16 row-major. 512 thr = 8 waves (2M x 4N),
// wave tile 128x64. LDS: As/Bs [2 buf][2 kh][256 rows][32 cols] = 128 KiB total.
//
// vmcnt ledger (per-wave gl2lds instructions; 2 per STAGE):
//   prologue: issue A0,B0,A1,B1 of tile0 (8), vmcnt(0)+barrier  -> 0 in flight.
//   tile t (buf c, stage tile t+1 -> buf 1-c):
//     P0: read As[c][0] mi0-3 + Bs[c][0];  stage A0'          (out +2)
//     P1: read As[c][0] mi4-7;             stage B0'; vmcnt(4) (drains prev A1,B1)
//     P2: read As[c][1] mi0-3 + Bs[c][1];  stage A1'          (out +2)
//     P3: read As[c][1] mi4-7;             stage B1'; vmcnt(4) (drains A0',B0')
//   Every sub-buffer is in the drained-oldest-4 of a vmcnt(4)+barrier at least
//   2 phases before its first read; in-loop gl2lds order is pinned by the
//   memory-clobber asm barriers, so "oldest" is well-defined. Never drains to 0.

__global__ __launch_bounds__(512, 2) void k_gemm256(const unsigned short* __restrict__ A,
                                                    const unsigned short* __restrict__ B,
                                                    float* __restrict__ out,
                                                    const float* __restrict__ bias) {
  __shared__ __align__(16) unsigned short As[2][2][8192];  // [buf][kh][256*32]
  __shared__ __align__(16) unsigned short Bs[2][2][8192];

  const int tid  = threadIdx.x;
  const int lane = tid & 63;
  const int wave = tid >> 6;

  // XCD-bijective swizzle: 512 blocks, 8 XCDs, 64-block chunks (4 A-panel rows).
  const int id  = blockIdx.y * gridDim.x + blockIdx.x;
  const int nid = (id & 7) * 64 + (id >> 3);
  const int bx  = nid & 15;
  const int by  = nid >> 4;
  const int m0  = by * 256;
  const int n0  = bx * 256;

  const int waveM = (wave >> 2) << 7;   // 0 or 128
  const int waveN = (wave & 3) << 6;    // 0,64,128,192
  const int l15   = lane & 15;
  const int quad  = lane >> 4;

  // read-side swizzled chunk (shorts): quad ^ (row&3) ^ ((row>>2)&3), row ~ l15
  const int rsw = (quad ^ (l15 & 3) ^ ((l15 >> 2) & 3)) * 8;
  // stage-side: lane writes LDS chunk (lane&3) of row wave*16+(lane>>2) (+j*128);
  // source chunk pre-swizzled so LDS[row][c] = G[row][c ^ (row&3) ^ ((row>>2)&3)]
  const int srow   = wave * 16 + (lane >> 2);
  const int schunk = (lane & 3) ^ ((lane >> 2) & 3) ^ ((lane >> 4) & 3);

  floatx4 acc[8][4];
#pragma unroll
  for (int i = 0; i < 8; ++i)
#pragma unroll
    for (int j = 0; j < 4; ++j) acc[i][j] = (floatx4)0.0f;

#define STAGE(LDSHALF, GBASE, R0, KBYTE)                                          \
  {                                                                               \
    _Pragma("unroll")                                                             \
    for (int j_ = 0; j_ < 2; ++j_) {                                              \
      const char* src_ = (const char*)(GBASE) +                                   \
          (size_t)((R0) + j_ * 128 + srow) * (size_t)(GEMM_K * 2) +               \
          (size_t)(KBYTE) + schunk * 16;                                          \
      gl2lds16(src_, (char*)(LDSHALF) + j_ * 8192 + wave * 1024);                 \
    }                                                                             \
  }

#define PHASE(BUF, KH, MH, DO_STAGE, DO_VMCNT)                                    \
  {                                                                               \
    const unsigned short* pa_ = &As[BUF][KH][0];                                  \
    short8 af_[4];                                                                \
    if ((MH) == 0) {                                                              \
      const unsigned short* pb_ = &Bs[BUF][KH][0];                                \
      _Pragma("unroll")                                                           \
      for (int i_ = 0; i_ < 4; ++i_)                                              \
        bfv[i_] = *(const short8*)(pb_ + (waveN + i_ * 16 + l15) * 32 + rsw);     \
    }                                                                             \
    _Pragma("unroll")                                                             \
    for (int i_ = 0; i_ < 4; ++i_)                                                \
      af_[i_] = *(const short8*)(pa_ + (waveM + ((MH) * 4 + i_) * 16 + l15) * 32 + rsw); \
    DO_STAGE;                                                                     \
    if (DO_VMCNT) asm volatile("s_waitcnt vmcnt(4)" ::: "memory");                \
    asm volatile("s_barrier" ::: "memory");                                       \
    __builtin_amdgcn_sched_barrier(0);                                            \
    __builtin_amdgcn_s_setprio(1);                                                \
    _Pragma("unroll")                                                             \
    for (int i_ = 0; i_ < 4; ++i_)                                                \
      _Pragma("unroll")                                                           \
      for (int n_ = 0; n_ < 4; ++n_)                                              \
        acc[(MH) * 4 + i_][n_] = __builtin_amdgcn_mfma_f32_16x16x32_bf16(         \
            af_[i_], bfv[n_], acc[(MH) * 4 + i_][n_], 0, 0, 0);                   \
    __builtin_amdgcn_s_setprio(0);                                                \
    asm volatile("s_barrier" ::: "memory");                                       \
  }

#define KTILE(C, KTN)                                                             \
  {                                                                               \
    PHASE(C, 0, 0, STAGE(&As[1 - (C)][0][0], A, m0, (KTN) * 2), 0)                \
    PHASE(C, 0, 1, STAGE(&Bs[1 - (C)][0][0], B, n0, (KTN) * 2), 1)                \
    PHASE(C, 1, 0, STAGE(&As[1 - (C)][1][0], A, m0, (KTN) * 2 + 64), 0)           \
    PHASE(C, 1, 1, STAGE(&Bs[1 - (C)][1][0], B, n0, (KTN) * 2 + 64), 1)           \
  }

  // prologue: stage tile0 into buf0, full drain once (order-safe), barrier.
  STAGE(&As[0][0][0], A, m0, 0);
  STAGE(&Bs[0][0][0], B, n0, 0);
  STAGE(&As[0][1][0], A, m0, 64);
  STAGE(&Bs[0][1][0], B, n0, 64);
  asm volatile("s_waitcnt vmcnt(0)" ::: "memory");
  asm volatile("s_barrier" ::: "memory");

  short8 bfv[4];
  for (int kt = 0; kt < GEMM_K; kt += 128) {
    const int ktn0 = kt + 64;                                  // tile for buf1
    KTILE(0, ktn0)
    const int ktn1 = (kt + 128 < GEMM_K) ? (kt + 128) : 0;     // wrap: harmless restage
    KTILE(1, ktn1)
  }

#undef KTILE
#undef PHASE
#undef STAGE

  // epilogue: C/D layout col = lane&15, row = quad*4 + reg (proven m89/m91).
#pragma unroll
  for (int ni = 0; ni < 4; ++ni) {
    const int col = n0 + waveN + ni * 16 + l15;
    const float bv = bias[col];
#pragma unroll
    for (int mi = 0; mi < 8; ++mi) {
      const int row0 = m0 + waveM + mi * 16 + quad * 4;
#pragma unroll
      for (int r = 0; r < 4; ++r)
        out[(size_t)(row0 + r) * DOUT + col] = acc[mi][ni][r] + bv;
    }
  }
}

extern "C" void kernel_launch(void* const* d_in, const int* in_sizes, int n_in,
                              void* d_out, int out_size, void* d_ws, size_t ws_size,
                              hipStream_t stream) {
  const float* x    = (const float*)d_in[0];
  const float* c1   = (const float*)d_in[1];
  const float* c2   = (const float*)d_in[2];
  const float* bias = (const float*)d_in[3];
  float* out = (float*)d_out;

  // workspace layout (100 MB total)
  char* ws = (char*)d_ws;
  unsigned short* xb  = (unsigned short*)ws;                               // 67108864 B
  unsigned short* Wb  = (unsigned short*)(ws + 67108864);                  // 33554432 B
  unsigned short* c1b = (unsigned short*)(ws + 67108864 + 33554432);       //  2097152 B
  unsigned short* c2t = (unsigned short*)(ws + 67108864 + 33554432 + 2097152);  // 2097152 B

  k_f32_to_bf16<<<(TOKENS * DIN) / 2048, 256, 0, stream>>>(x, xb, TOKENS * DIN);
  k_f32_to_bf16<<<(64 * 64 * RANK) / 2048, 256, 0, stream>>>(c1, c1b, 64 * 64 * RANK);
  k_transpose_c2<<<dim3(64, 4), 256, 0, stream>>>(c2, c2t);

  // t-GEMM: [4096 x 256] @ [4096 x 256]^T -> W bf16 (permuted store), BK=32 (R1-proven)
  k_gemm_bt<RANK, 32, true><<<dim3(32, 32), 256, 0, stream>>>(c1b, c2t, nullptr, Wb, nullptr);
  // main GEMM: 256^2 8-phase pipeline, [8192 x 4096] @ [4096 x 4096]^T + bias
  k_gemm256<<<dim3(16, 32), 512, 0, stream>>>(xb, Wb, out, bias);
}

// Round 2
// 509.856 us; speedup vs baseline: 1.0334x; 1.0334x over previous
//
#include <hip/hip_runtime.h>
#include <hip/hip_bf16.h>
#include <stdint.h>

// MPO linear: out = x @ W^T + bias, W[m1*64+m2, n1*64+n2] = sum_r c1[m1,n1,r] c2[r,m2,n2]
// R5: R4's 256x256 8-phase pipeline, with the LDS swizzle replaced by the
//     MEASURED-conflict-free st_16x32 involution (byte ^= ((byte>>9)&1)<<5,
//     i.e. 16B-chunk ^= (row>>2)&2 on [256][32]-short sub-buffers).
//     R4's hand-derived XOR (c ^ (row&3) ^ ((row>>2)&3)) measured 2.5e7
//     SQ_LDS_BANK_CONFLICT (~4 cyc extra per ds_read_b128, 2x LDS time,
//     MfmaUtil pinned at 38%). LDS is the in-phase critical path; this is
//     the single variable changed this round. Pipeline/vmcnt ledger identical.

#define TOKENS 8192
#define DIN    4096
#define DOUT   4096
#define RANK   256
#define GEMM_K 4096

typedef __attribute__((ext_vector_type(8))) short   short8;
typedef __attribute__((ext_vector_type(4))) float   floatx4;

__device__ __forceinline__ unsigned short f2bf(float f) {
  union { float f; unsigned u; } v; v.f = f;
  unsigned r = v.u + 0x7FFFu + ((v.u >> 16) & 1u);  // round-to-nearest-even
  return (unsigned short)(r >> 16);
}

__device__ __forceinline__ void gl2lds16(const void* g, void* l) {
  __builtin_amdgcn_global_load_lds(
      (const __attribute__((address_space(1))) unsigned int*)g,
      (__attribute__((address_space(3))) unsigned int*)l,
      16, 0, 0);
}

// ---- fp32 -> bf16 convert, n multiple of 2048 ----
__global__ __launch_bounds__(256) void k_f32_to_bf16(const float* __restrict__ src,
                                                     unsigned short* __restrict__ dst,
                                                     int n) {
  int i = (blockIdx.x * 256 + threadIdx.x) * 8;
  if (i >= n) return;
  float4 a = *(const float4*)(src + i);
  float4 b = *(const float4*)(src + i + 4);
  short8 o;
  o[0] = (short)f2bf(a.x); o[1] = (short)f2bf(a.y);
  o[2] = (short)f2bf(a.z); o[3] = (short)f2bf(a.w);
  o[4] = (short)f2bf(b.x); o[5] = (short)f2bf(b.y);
  o[6] = (short)f2bf(b.z); o[7] = (short)f2bf(b.w);
  *(short8*)(dst + i) = o;
}

// ---- core2 [256][4096] f32  ->  c2t [4096][256] bf16 (LDS tile transpose) ----
__global__ __launch_bounds__(256) void k_transpose_c2(const float* __restrict__ c2,
                                                      unsigned short* __restrict__ c2t) {
  __shared__ float tile[64][65];
  const int p0 = blockIdx.x * 64;
  const int r0 = blockIdx.y * 64;
  {
    const int px = threadIdx.x & 63;
    const int rb = threadIdx.x >> 6;           // 0..3
    for (int s = 0; s < 16; ++s) {
      int r = rb + s * 4;
      tile[r][px] = c2[(size_t)(r0 + r) * 4096 + p0 + px];
    }
  }
  __syncthreads();
  {
    const int rx = threadIdx.x & 63;
    const int pb = threadIdx.x >> 6;
    for (int s = 0; s < 16; ++s) {
      int p = pb + s * 4;
      c2t[(size_t)(p0 + p) * 256 + r0 + rx] = f2bf(tile[rx][p]);
    }
  }
}

// ---- R1-proven 128x128 BK=32 GEMM (kept for the small W-GEMM, K=256) ----
// C = A @ B^T. PERM=true: permuted bf16 store of W.
template <int K, int BK, bool PERM>
__global__ __launch_bounds__(256) void k_gemm_bt(const unsigned short* __restrict__ A,
                                                 const unsigned short* __restrict__ B,
                                                 float* __restrict__ outF,
                                                 unsigned short* __restrict__ outW,
                                                 const float* __restrict__ bias) {
  constexpr int ROWB   = BK * 2;
  constexpr int CM     = BK / 8 - 1;
  constexpr int ROUNDS = BK / 16;
  constexpr int KK     = BK / 32;

  __shared__ __align__(16) unsigned short As[128 * BK];
  __shared__ __align__(16) unsigned short Bs[128 * BK];

  const int tid  = threadIdx.x;
  const int lane = tid & 63;
  const int wave = tid >> 6;
  const int m0 = blockIdx.y * 128;
  const int n0 = blockIdx.x * 128;

  const int waveM = (wave & 1) * 64;
  const int waveN = (wave >> 1) * 64;
  const int l15  = lane & 15;
  const int quad = lane >> 4;

  floatx4 acc[4][4];
#pragma unroll
  for (int i = 0; i < 4; ++i)
#pragma unroll
    for (int j = 0; j < 4; ++j) acc[i][j] = (floatx4)0.0f;

  const size_t rowBytes = (size_t)K * 2;

  for (int kt = 0; kt < K; kt += BK) {
    __syncthreads();
#pragma unroll
    for (int j = 0; j < ROUNDS; ++j) {
      const int flat = (j * 4 + wave) * 1024 + lane * 16;
      const int row  = flat / ROWB;
      const int c    = (flat >> 4) & CM;
      const int cs   = c ^ (row & CM);
      const int ldsb = (j * 4 + wave) * 1024;
      gl2lds16((const char*)A + (size_t)(m0 + row) * rowBytes + (size_t)kt * 2 + cs * 16,
               (char*)As + ldsb);
      gl2lds16((const char*)B + (size_t)(n0 + row) * rowBytes + (size_t)kt * 2 + cs * 16,
               (char*)Bs + ldsb);
    }
    __syncthreads();

#pragma unroll
    for (int kk = 0; kk < KK; ++kk) {
      short8 af[4], bfr[4];
#pragma unroll
      for (int mi = 0; mi < 4; ++mi) {
        const int row = waveM + mi * 16 + l15;
        const int cs  = (kk * 4 + quad) ^ (row & CM);
        af[mi] = *(const short8*)(As + row * BK + cs * 8);
      }
#pragma unroll
      for (int ni = 0; ni < 4; ++ni) {
        const int row = waveN + ni * 16 + l15;
        const int cs  = (kk * 4 + quad) ^ (row & CM);
        bfr[ni] = *(const short8*)(Bs + row * BK + cs * 8);
      }
#pragma unroll
      for (int mi = 0; mi < 4; ++mi)
#pragma unroll
        for (int ni = 0; ni < 4; ++ni)
          acc[mi][ni] = __builtin_amdgcn_mfma_f32_16x16x32_bf16(af[mi], bfr[ni], acc[mi][ni], 0, 0, 0);
    }
  }

  if (!PERM) {
#pragma unroll
    for (int ni = 0; ni < 4; ++ni) {
      const int col = n0 + waveN + ni * 16 + l15;
      const float bv = bias[col];
#pragma unroll
      for (int mi = 0; mi < 4; ++mi) {
        const int rowb = m0 + waveM + mi * 16 + quad * 4;
#pragma unroll
        for (int r = 0; r < 4; ++r)
          outF[(size_t)(rowb + r) * DOUT + col] = acc[mi][ni][r] + bv;
      }
    }
  } else {
#pragma unroll
    for (int ni = 0; ni < 4; ++ni) {
      const int bcol = n0 + waveN + ni * 16 + l15;
      const int m2 = bcol >> 6, n2 = bcol & 63;
#pragma unroll
      for (int mi = 0; mi < 4; ++mi) {
        const int arow0 = m0 + waveM + mi * 16 + quad * 4;
#pragma unroll
        for (int r = 0; r < 4; ++r) {
          const int arow = arow0 + r;
          const int m1 = arow >> 6, n1 = arow & 63;
          outW[(size_t)(m1 * 64 + m2) * 4096 + (n1 * 64 + n2)] = f2bf(acc[mi][ni][r]);
        }
      }
    }
  }
}

// ---- R5: 256x256 8-phase deep-pipelined bf16 GEMM, C = A @ B^T + bias ----
// A:[8192][4096], B:[4096][4096] bf16 row-major. 512 thr = 8 waves (2M x 4N),
// wave tile 128x64. LDS: As/Bs [2 buf][2 kh][256 rows][32 cols] = 128 KiB total.
//
// LDS swizzle (st_16x32, measured conflict-free): within each [256][32]-short
// sub-buffer, 16B chunk c of row r holds global chunk c ^ ((r>>2)&2).
// Same involution applied on stage (source pre-swizzle, linear gl2lds dest)
// and read. Only row bit 3 participates; chunk bit 1 flips.
//
// vmcnt ledger (per-wave gl2lds instructions; 2 per STAGE):
//   prologue: issue A0,B0,A1,B1 of tile0 (8), vmcnt(0)+barrier  -> 0 in flight.
//   tile t (buf c, stage tile t+1 -> buf 1-c):
//     P0: read As[c][0] mi0-3 + Bs[c][0];  stage A0'          (out +2)
//     P1: read As[c][0] mi4-7;             stage B0'; vmcnt(4) (drains prev A1,B1)
//     P2: read As[c][1] mi0-3 + Bs[c][1];  stage A1'          (out +2)
//     P3: read As[c][1] mi4-7;             stage B1'; vmcnt(4) (drains A0',B0')
//   Every sub-buffer is in the drained-oldest-4 of a vmcnt(4)+barrier at least
//   2 phases before its first read; never drains to 0 in the main loop.

__global__ __launch_bounds__(512, 2) void k_gemm256(const unsigned short* __restrict__ A,
                                                    const unsigned short* __restrict__ B,
                                                    float* __restrict__ out,
                                                    const float* __restrict__ bias) {
  __shared__ __align__(16) unsigned short As[2][2][8192];  // [buf][kh][256*32]
  __shared__ __align__(16) unsigned short Bs[2][2][8192];

  const int tid  = threadIdx.x;
  const int lane = tid & 63;
  const int wave = tid >> 6;

  // XCD-bijective swizzle: 512 blocks, 8 XCDs, 64-block chunks (4 A-panel rows).
  const int id  = blockIdx.y * gridDim.x + blockIdx.x;
  const int nid = (id & 7) * 64 + (id >> 3);
  const int bx  = nid & 15;
  const int by  = nid >> 4;
  const int m0  = by * 256;
  const int n0  = bx * 256;

  const int waveM = (wave >> 2) << 7;   // 0 or 128
  const int waveN = (wave & 3) << 6;    // 0,64,128,192
  const int l15   = lane & 15;
  const int quad  = lane >> 4;

  // read-side swizzled chunk (shorts): st_16x32 -> chunk = quad ^ ((row>>2)&2);
  // row = base(mult of 16) + l15, so (row>>2)&2 = (l15>>2)&2.
  const int rsw = (quad ^ ((l15 >> 2) & 2)) * 8;
  // stage-side: lane writes LDS chunk (lane&3) of row wave*16+(lane>>2) (+j*128);
  // source chunk = (lane&3) ^ ((row>>2)&2); (row>>2)&2 = (lane>>4)&2 (j*128 no-op).
  const int srow   = wave * 16 + (lane >> 2);
  const int schunk = (lane & 3) ^ ((lane >> 4) & 2);

  floatx4 acc[8][4];
#pragma unroll
  for (int i = 0; i < 8; ++i)
#pragma unroll
    for (int j = 0; j < 4; ++j) acc[i][j] = (floatx4)0.0f;

#define STAGE(LDSHALF, GBASE, R0, KBYTE)                                          \
  {                                                                               \
    _Pragma("unroll")                                                             \
    for (int j_ = 0; j_ < 2; ++j_) {                                              \
      const char* src_ = (const char*)(GBASE) +                                   \
          (size_t)((R0) + j_ * 128 + srow) * (size_t)(GEMM_K * 2) +               \
          (size_t)(KBYTE) + schunk * 16;                                          \
      gl2lds16(src_, (char*)(LDSHALF) + j_ * 8192 + wave * 1024);                 \
    }                                                                             \
  }

#define PHASE(BUF, KH, MH, DO_STAGE, DO_VMCNT)                                    \
  {                                                                               \
    const unsigned short* pa_ = &As[BUF][KH][0];                                  \
    short8 af_[4];                                                                \
    if ((MH) == 0) {                                                              \
      const unsigned short* pb_ = &Bs[BUF][KH][0];                                \
      _Pragma("unroll")                                                           \
      for (int i_ = 0; i_ < 4; ++i_)                                              \
        bfv[i_] = *(const short8*)(pb_ + (waveN + i_ * 16 + l15) * 32 + rsw);     \
    }                                                                             \
    _Pragma("unroll")                                                             \
    for (int i_ = 0; i_ < 4; ++i_)                                                \
      af_[i_] = *(const short8*)(pa_ + (waveM + ((MH) * 4 + i_) * 16 + l15) * 32 + rsw); \
    DO_STAGE;                                                                     \
    if (DO_VMCNT) asm volatile("s_waitcnt vmcnt(4)" ::: "memory");                \
    asm volatile("s_barrier" ::: "memory");                                       \
    __builtin_amdgcn_sched_barrier(0);                                            \
    __builtin_amdgcn_s_setprio(1);                                                \
    _Pragma("unroll")                                                             \
    for (int i_ = 0; i_ < 4; ++i_)                                                \
      _Pragma("unroll")                                                           \
      for (int n_ = 0; n_ < 4; ++n_)                                              \
        acc[(MH) * 4 + i_][n_] = __builtin_amdgcn_mfma_f32_16x16x32_bf16(         \
            af_[i_], bfv[n_], acc[(MH) * 4 + i_][n_], 0, 0, 0);                   \
    __builtin_amdgcn_s_setprio(0);                                                \
    asm volatile("s_barrier" ::: "memory");                                       \
  }

#define KTILE(C, KTN)                                                             \
  {                                                                               \
    PHASE(C, 0, 0, STAGE(&As[1 - (C)][0][0], A, m0, (KTN) * 2), 0)                \
    PHASE(C, 0, 1, STAGE(&Bs[1 - (C)][0][0], B, n0, (KTN) * 2), 1)                \
    PHASE(C, 1, 0, STAGE(&As[1 - (C)][1][0], A, m0, (KTN) * 2 + 64), 0)           \
    PHASE(C, 1, 1, STAGE(&Bs[1 - (C)][1][0], B, n0, (KTN) * 2 + 64), 1)           \
  }

  // prologue: stage tile0 into buf0, full drain once (order-safe), barrier.
  STAGE(&As[0][0][0], A, m0, 0);
  STAGE(&Bs[0][0][0], B, n0, 0);
  STAGE(&As[0][1][0], A, m0, 64);
  STAGE(&Bs[0][1][0], B, n0, 64);
  asm volatile("s_waitcnt vmcnt(0)" ::: "memory");
  asm volatile("s_barrier" ::: "memory");

  short8 bfv[4];
  for (int kt = 0; kt < GEMM_K; kt += 128) {
    const int ktn0 = kt + 64;                                  // tile for buf1
    KTILE(0, ktn0)
    const int ktn1 = (kt + 128 < GEMM_K) ? (kt + 128) : 0;     // wrap: harmless restage
    KTILE(1, ktn1)
  }

#undef KTILE
#undef PHASE
#undef STAGE

  // epilogue: C/D layout col = lane&15, row = quad*4 + reg (proven m89/m91).
#pragma unroll
  for (int ni = 0; ni < 4; ++ni) {
    const int col = n0 + waveN + ni * 16 + l15;
    const float bv = bias[col];
#pragma unroll
    for (int mi = 0; mi < 8; ++mi) {
      const int row0 = m0 + waveM + mi * 16 + quad * 4;
#pragma unroll
      for (int r = 0; r < 4; ++r)
        out[(size_t)(row0 + r) * DOUT + col] = acc[mi][ni][r] + bv;
    }
  }
}

extern "C" void kernel_launch(void* const* d_in, const int* in_sizes, int n_in,
                              void* d_out, int out_size, void* d_ws, size_t ws_size,
                              hipStream_t stream) {
  const float* x    = (const float*)d_in[0];
  const float* c1   = (const float*)d_in[1];
  const float* c2   = (const float*)d_in[2];
  const float* bias = (const float*)d_in[3];
  float* out = (float*)d_out;

  // workspace layout (100 MB total)
  char* ws = (char*)d_ws;
  unsigned short* xb  = (unsigned short*)ws;                               // 67108864 B
  unsigned short* Wb  = (unsigned short*)(ws + 67108864);                  // 33554432 B
  unsigned short* c1b = (unsigned short*)(ws + 67108864 + 33554432);       //  2097152 B
  unsigned short* c2t = (unsigned short*)(ws + 67108864 + 33554432 + 2097152);  // 2097152 B

  k_f32_to_bf16<<<(TOKENS * DIN) / 2048, 256, 0, stream>>>(x, xb, TOKENS * DIN);
  k_f32_to_bf16<<<(64 * 64 * RANK) / 2048, 256, 0, stream>>>(c1, c1b, 64 * 64 * RANK);
  k_transpose_c2<<<dim3(64, 4), 256, 0, stream>>>(c2, c2t);

  // t-GEMM: [4096 x 256] @ [4096 x 256]^T -> W bf16 (permuted store), BK=32 (R1-proven)
  k_gemm_bt<RANK, 32, true><<<dim3(32, 32), 256, 0, stream>>>(c1b, c2t, nullptr, Wb, nullptr);
  // main GEMM: 256^2 8-phase pipeline, [8192 x 4096] @ [4096 x 4096]^T + bias
  k_gemm256<<<dim3(16, 32), 512, 0, stream>>>(xb, Wb, out, bias);
}

// Round 3
// 506.893 us; speedup vs baseline: 1.0394x; 1.0058x over previous
//
#include <hip/hip_runtime.h>
#include <hip/hip_bf16.h>
#include <stdint.h>

// MPO linear: out = x @ W^T + bias, W[m1*64+m2, n1*64+n2] = sum_r c1[m1,n1,r] c2[r,m2,n2]
// R6: one-window-ahead register pipeline for the 256x256 GEMM.
//     R5 showed conflicts=0 but MfmaUtil stuck at 40%: each phase's ds_reads were
//     fully drained before that phase's MFMA (LDS pipe and MFMA pipe alternated,
//     never overlapped). Now window W(p) = { ds_reads for W(p+1)'s fragments |
//     1 sub-buffer gl2lds stage | sched_barrier | MFMA(p) from regs read in W(p-1) }.
//     Reads of W(p) complete on the LDS pipe UNDER MFMA(p); lgkm wait before
//     MFMA is ~free (operands read one window earlier).
//     Barriers: 2 per KTILE (W1,W3 entry) with vmcnt(2) — never drains to 0.
//     vmcnt ledger (per-wave gl2lds, 2 per STAGE), steady state:
//       enter W1: in-flight {A1^,B1^,A0'}=6? no: {prevA1,prevB1 drained earlier}...
//       prologue->0; W0 +A0'(2)=2; W1 vmcnt(2) [drains prev A1,B1; first iter noop],
//       +B0'(2)=4; W2 +A1'(2)=6; W3 vmcnt(2) drains A0',B0' ->2, +B1'(2)=4;
//       next W0 +A0''=6; next W1 vmcnt(2) drains A1',B1' ->2. Closes. Never 0.
//     Hazard proofs (2 barriers/KTILE suffice):
//       read-after-stage: every sub-buffer read is preceded by the vmcnt(2)+barrier
//         that drains it, >=2 windows (>1000cy > 900cy HBM) after issue.
//       stage-after-read: restage of buf C sub-buffer X happens >=1 barrier after
//         the last MFMA consuming X (per-wave race checked both directions).

#define TOKENS 8192
#define DIN    4096
#define DOUT   4096
#define RANK   256
#define GEMM_K 4096

typedef __attribute__((ext_vector_type(8))) short   short8;
typedef __attribute__((ext_vector_type(4))) float   floatx4;

__device__ __forceinline__ unsigned short f2bf(float f) {
  union { float f; unsigned u; } v; v.f = f;
  unsigned r = v.u + 0x7FFFu + ((v.u >> 16) & 1u);  // round-to-nearest-even
  return (unsigned short)(r >> 16);
}

__device__ __forceinline__ void gl2lds16(const void* g, void* l) {
  __builtin_amdgcn_global_load_lds(
      (const __attribute__((address_space(1))) unsigned int*)g,
      (__attribute__((address_space(3))) unsigned int*)l,
      16, 0, 0);
}

// ---- fp32 -> bf16 convert, n multiple of 2048 ----
__global__ __launch_bounds__(256) void k_f32_to_bf16(const float* __restrict__ src,
                                                     unsigned short* __restrict__ dst,
                                                     int n) {
  int i = (blockIdx.x * 256 + threadIdx.x) * 8;
  if (i >= n) return;
  float4 a = *(const float4*)(src + i);
  float4 b = *(const float4*)(src + i + 4);
  short8 o;
  o[0] = (short)f2bf(a.x); o[1] = (short)f2bf(a.y);
  o[2] = (short)f2bf(a.z); o[3] = (short)f2bf(a.w);
  o[4] = (short)f2bf(b.x); o[5] = (short)f2bf(b.y);
  o[6] = (short)f2bf(b.z); o[7] = (short)f2bf(b.w);
  *(short8*)(dst + i) = o;
}

// ---- core2 [256][4096] f32  ->  c2t [4096][256] bf16 (LDS tile transpose) ----
__global__ __launch_bounds__(256) void k_transpose_c2(const float* __restrict__ c2,
                                                      unsigned short* __restrict__ c2t) {
  __shared__ float tile[64][65];
  const int p0 = blockIdx.x * 64;
  const int r0 = blockIdx.y * 64;
  {
    const int px = threadIdx.x & 63;
    const int rb = threadIdx.x >> 6;           // 0..3
    for (int s = 0; s < 16; ++s) {
      int r = rb + s * 4;
      tile[r][px] = c2[(size_t)(r0 + r) * 4096 + p0 + px];
    }
  }
  __syncthreads();
  {
    const int rx = threadIdx.x & 63;
    const int pb = threadIdx.x >> 6;
    for (int s = 0; s < 16; ++s) {
      int p = pb + s * 4;
      c2t[(size_t)(p0 + p) * 256 + r0 + rx] = f2bf(tile[rx][p]);
    }
  }
}

// ---- R1-proven 128x128 BK=32 GEMM (kept for the small W-GEMM, K=256) ----
template <int K, int BK, bool PERM>
__global__ __launch_bounds__(256) void k_gemm_bt(const unsigned short* __restrict__ A,
                                                 const unsigned short* __restrict__ B,
                                                 float* __restrict__ outF,
                                                 unsigned short* __restrict__ outW,
                                                 const float* __restrict__ bias) {
  constexpr int ROWB   = BK * 2;
  constexpr int CM     = BK / 8 - 1;
  constexpr int ROUNDS = BK / 16;
  constexpr int KK     = BK / 32;

  __shared__ __align__(16) unsigned short As[128 * BK];
  __shared__ __align__(16) unsigned short Bs[128 * BK];

  const int tid  = threadIdx.x;
  const int lane = tid & 63;
  const int wave = tid >> 6;
  const int m0 = blockIdx.y * 128;
  const int n0 = blockIdx.x * 128;

  const int waveM = (wave & 1) * 64;
  const int waveN = (wave >> 1) * 64;
  const int l15  = lane & 15;
  const int quad = lane >> 4;

  floatx4 acc[4][4];
#pragma unroll
  for (int i = 0; i < 4; ++i)
#pragma unroll
    for (int j = 0; j < 4; ++j) acc[i][j] = (floatx4)0.0f;

  const size_t rowBytes = (size_t)K * 2;

  for (int kt = 0; kt < K; kt += BK) {
    __syncthreads();
#pragma unroll
    for (int j = 0; j < ROUNDS; ++j) {
      const int flat = (j * 4 + wave) * 1024 + lane * 16;
      const int row  = flat / ROWB;
      const int c    = (flat >> 4) & CM;
      const int cs   = c ^ (row & CM);
      const int ldsb = (j * 4 + wave) * 1024;
      gl2lds16((const char*)A + (size_t)(m0 + row) * rowBytes + (size_t)kt * 2 + cs * 16,
               (char*)As + ldsb);
      gl2lds16((const char*)B + (size_t)(n0 + row) * rowBytes + (size_t)kt * 2 + cs * 16,
               (char*)Bs + ldsb);
    }
    __syncthreads();

#pragma unroll
    for (int kk = 0; kk < KK; ++kk) {
      short8 af[4], bfr[4];
#pragma unroll
      for (int mi = 0; mi < 4; ++mi) {
        const int row = waveM + mi * 16 + l15;
        const int cs  = (kk * 4 + quad) ^ (row & CM);
        af[mi] = *(const short8*)(As + row * BK + cs * 8);
      }
#pragma unroll
      for (int ni = 0; ni < 4; ++ni) {
        const int row = waveN + ni * 16 + l15;
        const int cs  = (kk * 4 + quad) ^ (row & CM);
        bfr[ni] = *(const short8*)(Bs + row * BK + cs * 8);
      }
#pragma unroll
      for (int mi = 0; mi < 4; ++mi)
#pragma unroll
        for (int ni = 0; ni < 4; ++ni)
          acc[mi][ni] = __builtin_amdgcn_mfma_f32_16x16x32_bf16(af[mi], bfr[ni], acc[mi][ni], 0, 0, 0);
    }
  }

  if (!PERM) {
#pragma unroll
    for (int ni = 0; ni < 4; ++ni) {
      const int col = n0 + waveN + ni * 16 + l15;
      const float bv = bias[col];
#pragma unroll
      for (int mi = 0; mi < 4; ++mi) {
        const int rowb = m0 + waveM + mi * 16 + quad * 4;
#pragma unroll
        for (int r = 0; r < 4; ++r)
          outF[(size_t)(rowb + r) * DOUT + col] = acc[mi][ni][r] + bv;
      }
    }
  } else {
#pragma unroll
    for (int ni = 0; ni < 4; ++ni) {
      const int bcol = n0 + waveN + ni * 16 + l15;
      const int m2 = bcol >> 6, n2 = bcol & 63;
#pragma unroll
      for (int mi = 0; mi < 4; ++mi) {
        const int arow0 = m0 + waveM + mi * 16 + quad * 4;
#pragma unroll
        for (int r = 0; r < 4; ++r) {
          const int arow = arow0 + r;
          const int m1 = arow >> 6, n1 = arow & 63;
          outW[(size_t)(m1 * 64 + m2) * 4096 + (n1 * 64 + n2)] = f2bf(acc[mi][ni][r]);
        }
      }
    }
  }
}

// ---- R6: 256x256 pipelined bf16 GEMM, C = A @ B^T + bias ----
// 512 thr = 8 waves (2M x 4N), wave tile 128x64.
// LDS: As/Bs [2 buf][2 kh][256 rows][32 shorts] = 128 KiB.
// st_16x32 swizzle (proven conflict-free R5): chunk ^= (row>>2)&2.
__global__ __launch_bounds__(512, 2) void k_gemm256(const unsigned short* __restrict__ A,
                                                    const unsigned short* __restrict__ B,
                                                    float* __restrict__ out,
                                                    const float* __restrict__ bias) {
  __shared__ __align__(16) unsigned short As[2][2][8192];  // [buf][kh][256*32]
  __shared__ __align__(16) unsigned short Bs[2][2][8192];

  const int tid  = threadIdx.x;
  const int lane = tid & 63;
  const int wave = tid >> 6;

  // XCD-bijective swizzle: 512 blocks, 8 XCDs, 64-block chunks.
  const int id  = blockIdx.y * gridDim.x + blockIdx.x;
  const int nid = (id & 7) * 64 + (id >> 3);
  const int bx  = nid & 15;
  const int by  = nid >> 4;
  const int m0  = by * 256;
  const int n0  = bx * 256;

  const int waveM = (wave >> 2) << 7;   // 0 or 128
  const int waveN = (wave & 3) << 6;    // 0,64,128,192
  const int l15   = lane & 15;
  const int quad  = lane >> 4;

  const int rsw = (quad ^ ((l15 >> 2) & 2)) * 8;          // read-side swizzled chunk
  const int srow   = wave * 16 + (lane >> 2);             // stage row
  const int schunk = (lane & 3) ^ ((lane >> 4) & 2);      // stage source chunk

  floatx4 acc[8][4];
#pragma unroll
  for (int i = 0; i < 8; ++i)
#pragma unroll
    for (int j = 0; j < 4; ++j) acc[i][j] = (floatx4)0.0f;

  // double-buffered fragment registers (static names, rule #20)
  short8 af0[4], af1[4], bfvA[4], bfvB[4];

#define STAGE(LDSHALF, GBASE, R0, KBYTE)                                          \
  {                                                                               \
    _Pragma("unroll")                                                             \
    for (int j_ = 0; j_ < 2; ++j_) {                                              \
      const char* src_ = (const char*)(GBASE) +                                   \
          (size_t)((R0) + j_ * 128 + srow) * (size_t)(GEMM_K * 2) +               \
          (size_t)(KBYTE) + schunk * 16;                                          \
      gl2lds16(src_, (char*)(LDSHALF) + j_ * 8192 + wave * 1024);                 \
    }                                                                             \
  }

#define READ_AF(DST, BUF, KH, MH)                                                 \
  _Pragma("unroll")                                                               \
  for (int i_ = 0; i_ < 4; ++i_)                                                  \
    DST[i_] = *(const short8*)(&As[BUF][KH][0] +                                  \
               (waveM + ((MH) * 4 + i_) * 16 + l15) * 32 + rsw);

#define READ_BF(DST, BUF, KH)                                                     \
  _Pragma("unroll")                                                               \
  for (int n_ = 0; n_ < 4; ++n_)                                                  \
    DST[n_] = *(const short8*)(&Bs[BUF][KH][0] +                                  \
               (waveN + n_ * 16 + l15) * 32 + rsw);

#define MFMA16(AF, BF, MH)                                                        \
  __builtin_amdgcn_s_setprio(1);                                                  \
  _Pragma("unroll")                                                               \
  for (int i_ = 0; i_ < 4; ++i_)                                                  \
    _Pragma("unroll")                                                             \
    for (int n_ = 0; n_ < 4; ++n_)                                                \
      acc[(MH) * 4 + i_][n_] = __builtin_amdgcn_mfma_f32_16x16x32_bf16(           \
          AF[i_], BF[n_], acc[(MH) * 4 + i_][n_], 0, 0, 0);                       \
  __builtin_amdgcn_s_setprio(0);

#define SYNC2()                                                                   \
  asm volatile("s_waitcnt vmcnt(2)" ::: "memory");                                \
  asm volatile("s_barrier" ::: "memory");

  // KTILE(C, KTN): compute K-range held in buf C; stage k-offset KTN into buf 1-C.
#define KTILE(C, KTN)                                                             \
  { /* W0: MFMA (C,kh0,mh0); read (C,kh0,mh1); stage A0' */                       \
    READ_AF(af1, C, 0, 1)                                                         \
    STAGE(&As[1 - (C)][0][0], A, m0, (KTN) * 2)                                   \
    __builtin_amdgcn_sched_barrier(0);                                            \
    MFMA16(af0, bfvA, 0)                                                          \
    /* W1: sync; MFMA (C,kh0,mh1); read (C,kh1,mh0)+bfvB; stage B0' */            \
    SYNC2()                                                                       \
    READ_AF(af0, C, 1, 0)                                                         \
    READ_BF(bfvB, C, 1)                                                           \
    STAGE(&Bs[1 - (C)][0][0], B, n0, (KTN) * 2)                                   \
    __builtin_amdgcn_sched_barrier(0);                                            \
    MFMA16(af1, bfvA, 1)                                                          \
    /* W2: MFMA (C,kh1,mh0); read (C,kh1,mh1); stage A1' */                       \
    READ_AF(af1, C, 1, 1)                                                         \
    STAGE(&As[1 - (C)][1][0], A, m0, (KTN) * 2 + 64)                              \
    __builtin_amdgcn_sched_barrier(0);                                            \
    MFMA16(af0, bfvB, 0)                                                          \
    /* W3: sync; MFMA (C,kh1,mh1); read next-tile (1-C,kh0,mh0)+bfvA; stage B1' */\
    SYNC2()                                                                       \
    READ_AF(af0, 1 - (C), 0, 0)                                                   \
    READ_BF(bfvA, 1 - (C), 0)                                                     \
    STAGE(&Bs[1 - (C)][1][0], B, n0, (KTN) * 2 + 64)                              \
    __builtin_amdgcn_sched_barrier(0);                                            \
    MFMA16(af1, bfvB, 1)                                                          \
  }

  // prologue: stage tile0 into buf0, drain fully once, prime W0's operands.
  STAGE(&As[0][0][0], A, m0, 0);
  STAGE(&Bs[0][0][0], B, n0, 0);
  STAGE(&As[0][1][0], A, m0, 64);
  STAGE(&Bs[0][1][0], B, n0, 64);
  asm volatile("s_waitcnt vmcnt(0)" ::: "memory");
  asm volatile("s_barrier" ::: "memory");
  READ_AF(af0, 0, 0, 0)
  READ_BF(bfvA, 0, 0)

  for (int kt = 0; kt < GEMM_K; kt += 128) {
    KTILE(0, kt + 64)
    const int ktn1 = (kt + 128 < GEMM_K) ? (kt + 128) : 0;   // wrap: harmless restage
    KTILE(1, ktn1)
  }

#undef KTILE
#undef SYNC2
#undef MFMA16
#undef READ_BF
#undef READ_AF
#undef STAGE

  // epilogue: C/D layout col = lane&15, row = quad*4 + reg (proven m89/m91).
#pragma unroll
  for (int ni = 0; ni < 4; ++ni) {
    const int col = n0 + waveN + ni * 16 + l15;
    const float bv = bias[col];
#pragma unroll
    for (int mi = 0; mi < 8; ++mi) {
      const int row0 = m0 + waveM + mi * 16 + quad * 4;
#pragma unroll
      for (int r = 0; r < 4; ++r)
        out[(size_t)(row0 + r) * DOUT + col] = acc[mi][ni][r] + bv;
    }
  }
}

extern "C" void kernel_launch(void* const* d_in, const int* in_sizes, int n_in,
                              void* d_out, int out_size, void* d_ws, size_t ws_size,
                              hipStream_t stream) {
  const float* x    = (const float*)d_in[0];
  const float* c1   = (const float*)d_in[1];
  const float* c2   = (const float*)d_in[2];
  const float* bias = (const float*)d_in[3];
  float* out = (float*)d_out;

  // workspace layout (100 MB total)
  char* ws = (char*)d_ws;
  unsigned short* xb  = (unsigned short*)ws;                               // 67108864 B
  unsigned short* Wb  = (unsigned short*)(ws + 67108864);                  // 33554432 B
  unsigned short* c1b = (unsigned short*)(ws + 67108864 + 33554432);       //  2097152 B
  unsigned short* c2t = (unsigned short*)(ws + 67108864 + 33554432 + 2097152);  // 2097152 B

  k_f32_to_bf16<<<(TOKENS * DIN) / 2048, 256, 0, stream>>>(x, xb, TOKENS * DIN);
  k_f32_to_bf16<<<(64 * 64 * RANK) / 2048, 256, 0, stream>>>(c1, c1b, 64 * 64 * RANK);
  k_transpose_c2<<<dim3(64, 4), 256, 0, stream>>>(c2, c2t);

  // t-GEMM: [4096 x 256] @ [4096 x 256]^T -> W bf16 (permuted store), BK=32 (R1-proven)
  k_gemm_bt<RANK, 32, true><<<dim3(32, 32), 256, 0, stream>>>(c1b, c2t, nullptr, Wb, nullptr);
  // main GEMM: 256^2 one-window-ahead pipeline, [8192 x 4096] @ [4096 x 4096]^T + bias
  k_gemm256<<<dim3(16, 32), 512, 0, stream>>>(xb, Wb, out, bias);
}

// Round 4
// 488.313 us; speedup vs baseline: 1.0789x; 1.0380x over previous
//
#include <hip/hip_runtime.h>
#include <hip/hip_bf16.h>
#include <stdint.h>

// MPO linear: out = x @ W^T + bias, W[m1*64+m2, n1*64+n2] = sum_r c1[m1,n1,r] c2[r,m2,n2]
// R7: asm ds_read_b128 + hand-counted lgkmcnt for the 256x256 GEMM.
//     R6 counters: window = 1300 cyc = MFMA(620) + LDS-read(576) + LDS-write(128):
//     pipes fully SERIALIZED. Cause: compiler inserts conservative lgkmcnt(~0)
//     before each MFMA cluster, draining the current window's ds_reads (not just
//     last window's operands). Fix (HK technique): reads via inline-asm
//     ds_read_b128 (compiler emits no waits for asm outputs) + explicit
//     s_waitcnt lgkmcnt(N) where N = reads issued THIS window (4 on W0/W2,
//     8 on W1/W3) + sched_barrier(0) (rule #18). MFMA then overlaps the
//     in-flight reads for the next window.
//     Wait ledger (per-wave ds_reads, issue order ...W3prev(8),W0(4),W1(8),...):
//       W0 LGKM(4): drains W3prev's 8 (operands af0,bfvA)   -> also guarantees
//         cross-wave stage-after-read safety at W1's barrier.
//       W1 LGKM(8): drains W0's 4 (af1).
//       W2 LGKM(4): drains W1's 8 (af0,bfvB).
//       W3 LGKM(8): drains W2's 4 (af1).
//     vmcnt(2) ledger identical to R6 (validated): drains exactly the staged
//     sub-buffers 2 windows before their first read; never 0 in the loop.

#define TOKENS 8192
#define DIN    4096
#define DOUT   4096
#define RANK   256
#define GEMM_K 4096

typedef __attribute__((ext_vector_type(8))) short   short8;
typedef __attribute__((ext_vector_type(4))) float   floatx4;

__device__ __forceinline__ unsigned short f2bf(float f) {
  union { float f; unsigned u; } v; v.f = f;
  unsigned r = v.u + 0x7FFFu + ((v.u >> 16) & 1u);  // round-to-nearest-even
  return (unsigned short)(r >> 16);
}

__device__ __forceinline__ void gl2lds16(const void* g, void* l) {
  __builtin_amdgcn_global_load_lds(
      (const __attribute__((address_space(1))) unsigned int*)g,
      (__attribute__((address_space(3))) unsigned int*)l,
      16, 0, 0);
}

// LDS byte offset of a generic pointer (AS3 pointers are 32-bit offsets).
__device__ __forceinline__ unsigned ldsaddr(const void* p) {
  return (unsigned)(size_t)(const __attribute__((address_space(3))) char*)p;
}

// ---- fp32 -> bf16 convert, n multiple of 2048 ----
__global__ __launch_bounds__(256) void k_f32_to_bf16(const float* __restrict__ src,
                                                     unsigned short* __restrict__ dst,
                                                     int n) {
  int i = (blockIdx.x * 256 + threadIdx.x) * 8;
  if (i >= n) return;
  float4 a = *(const float4*)(src + i);
  float4 b = *(const float4*)(src + i + 4);
  short8 o;
  o[0] = (short)f2bf(a.x); o[1] = (short)f2bf(a.y);
  o[2] = (short)f2bf(a.z); o[3] = (short)f2bf(a.w);
  o[4] = (short)f2bf(b.x); o[5] = (short)f2bf(b.y);
  o[6] = (short)f2bf(b.z); o[7] = (short)f2bf(b.w);
  *(short8*)(dst + i) = o;
}

// ---- core2 [256][4096] f32  ->  c2t [4096][256] bf16 (LDS tile transpose) ----
__global__ __launch_bounds__(256) void k_transpose_c2(const float* __restrict__ c2,
                                                      unsigned short* __restrict__ c2t) {
  __shared__ float tile[64][65];
  const int p0 = blockIdx.x * 64;
  const int r0 = blockIdx.y * 64;
  {
    const int px = threadIdx.x & 63;
    const int rb = threadIdx.x >> 6;           // 0..3
    for (int s = 0; s < 16; ++s) {
      int r = rb + s * 4;
      tile[r][px] = c2[(size_t)(r0 + r) * 4096 + p0 + px];
    }
  }
  __syncthreads();
  {
    const int rx = threadIdx.x & 63;
    const int pb = threadIdx.x >> 6;
    for (int s = 0; s < 16; ++s) {
      int p = pb + s * 4;
      c2t[(size_t)(p0 + p) * 256 + r0 + rx] = f2bf(tile[rx][p]);
    }
  }
}

// ---- R1-proven 128x128 BK=32 GEMM (kept for the small W-GEMM, K=256) ----
template <int K, int BK, bool PERM>
__global__ __launch_bounds__(256) void k_gemm_bt(const unsigned short* __restrict__ A,
                                                 const unsigned short* __restrict__ B,
                                                 float* __restrict__ outF,
                                                 unsigned short* __restrict__ outW,
                                                 const float* __restrict__ bias) {
  constexpr int ROWB   = BK * 2;
  constexpr int CM     = BK / 8 - 1;
  constexpr int ROUNDS = BK / 16;
  constexpr int KK     = BK / 32;

  __shared__ __align__(16) unsigned short As[128 * BK];
  __shared__ __align__(16) unsigned short Bs[128 * BK];

  const int tid  = threadIdx.x;
  const int lane = tid & 63;
  const int wave = tid >> 6;
  const int m0 = blockIdx.y * 128;
  const int n0 = blockIdx.x * 128;

  const int waveM = (wave & 1) * 64;
  const int waveN = (wave >> 1) * 64;
  const int l15  = lane & 15;
  const int quad = lane >> 4;

  floatx4 acc[4][4];
#pragma unroll
  for (int i = 0; i < 4; ++i)
#pragma unroll
    for (int j = 0; j < 4; ++j) acc[i][j] = (floatx4)0.0f;

  const size_t rowBytes = (size_t)K * 2;

  for (int kt = 0; kt < K; kt += BK) {
    __syncthreads();
#pragma unroll
    for (int j = 0; j < ROUNDS; ++j) {
      const int flat = (j * 4 + wave) * 1024 + lane * 16;
      const int row  = flat / ROWB;
      const int c    = (flat >> 4) & CM;
      const int cs   = c ^ (row & CM);
      const int ldsb = (j * 4 + wave) * 1024;
      gl2lds16((const char*)A + (size_t)(m0 + row) * rowBytes + (size_t)kt * 2 + cs * 16,
               (char*)As + ldsb);
      gl2lds16((const char*)B + (size_t)(n0 + row) * rowBytes + (size_t)kt * 2 + cs * 16,
               (char*)Bs + ldsb);
    }
    __syncthreads();

#pragma unroll
    for (int kk = 0; kk < KK; ++kk) {
      short8 af[4], bfr[4];
#pragma unroll
      for (int mi = 0; mi < 4; ++mi) {
        const int row = waveM + mi * 16 + l15;
        const int cs  = (kk * 4 + quad) ^ (row & CM);
        af[mi] = *(const short8*)(As + row * BK + cs * 8);
      }
#pragma unroll
      for (int ni = 0; ni < 4; ++ni) {
        const int row = waveN + ni * 16 + l15;
        const int cs  = (kk * 4 + quad) ^ (row & CM);
        bfr[ni] = *(const short8*)(Bs + row * BK + cs * 8);
      }
#pragma unroll
      for (int mi = 0; mi < 4; ++mi)
#pragma unroll
        for (int ni = 0; ni < 4; ++ni)
          acc[mi][ni] = __builtin_amdgcn_mfma_f32_16x16x32_bf16(af[mi], bfr[ni], acc[mi][ni], 0, 0, 0);
    }
  }

  if (!PERM) {
#pragma unroll
    for (int ni = 0; ni < 4; ++ni) {
      const int col = n0 + waveN + ni * 16 + l15;
      const float bv = bias[col];
#pragma unroll
      for (int mi = 0; mi < 4; ++mi) {
        const int rowb = m0 + waveM + mi * 16 + quad * 4;
#pragma unroll
        for (int r = 0; r < 4; ++r)
          outF[(size_t)(rowb + r) * DOUT + col] = acc[mi][ni][r] + bv;
      }
    }
  } else {
#pragma unroll
    for (int ni = 0; ni < 4; ++ni) {
      const int bcol = n0 + waveN + ni * 16 + l15;
      const int m2 = bcol >> 6, n2 = bcol & 63;
#pragma unroll
      for (int mi = 0; mi < 4; ++mi) {
        const int arow0 = m0 + waveM + mi * 16 + quad * 4;
#pragma unroll
        for (int r = 0; r < 4; ++r) {
          const int arow = arow0 + r;
          const int m1 = arow >> 6, n1 = arow & 63;
          outW[(size_t)(m1 * 64 + m2) * 4096 + (n1 * 64 + n2)] = f2bf(acc[mi][ni][r]);
        }
      }
    }
  }
}

// ---- R7: 256x256 pipelined bf16 GEMM, C = A @ B^T + bias ----
// 512 thr = 8 waves (2M x 4N), wave tile 128x64.
// LDS: As/Bs [2 buf][2 kh][256 rows][32 shorts] = 128 KiB.
// st_16x32 swizzle (proven conflict-free R5): chunk ^= (row>>2)&2.
__global__ __launch_bounds__(512, 2) void k_gemm256(const unsigned short* __restrict__ A,
                                                    const unsigned short* __restrict__ B,
                                                    float* __restrict__ out,
                                                    const float* __restrict__ bias) {
  __shared__ __align__(16) unsigned short As[2][2][8192];  // [buf][kh][256*32]
  __shared__ __align__(16) unsigned short Bs[2][2][8192];

  const int tid  = threadIdx.x;
  const int lane = tid & 63;
  const int wave = tid >> 6;

  // XCD-bijective swizzle: 512 blocks, 8 XCDs, 64-block chunks.
  const int id  = blockIdx.y * gridDim.x + blockIdx.x;
  const int nid = (id & 7) * 64 + (id >> 3);
  const int bx  = nid & 15;
  const int by  = nid >> 4;
  const int m0  = by * 256;
  const int n0  = bx * 256;

  const int waveM = (wave >> 2) << 7;   // 0 or 128
  const int waveN = (wave & 3) << 6;    // 0,64,128,192
  const int l15   = lane & 15;
  const int quad  = lane >> 4;

  const int rsw = (quad ^ ((l15 >> 2) & 2)) * 8;          // read-side swizzled chunk
  const int srow   = wave * 16 + (lane >> 2);             // stage row
  const int schunk = (lane & 3) ^ ((lane >> 4) & 2);      // stage source chunk

  floatx4 acc[8][4];
#pragma unroll
  for (int i = 0; i < 8; ++i)
#pragma unroll
    for (int j = 0; j < 4; ++j) acc[i][j] = (floatx4)0.0f;

  // double-buffered fragment registers (static names, rule #20)
  short8 af0[4], af1[4], bfvA[4], bfvB[4];

#define STAGE(LDSHALF, GBASE, R0, KBYTE)                                          \
  {                                                                               \
    _Pragma("unroll")                                                             \
    for (int j_ = 0; j_ < 2; ++j_) {                                              \
      const char* src_ = (const char*)(GBASE) +                                   \
          (size_t)((R0) + j_ * 128 + srow) * (size_t)(GEMM_K * 2) +               \
          (size_t)(KBYTE) + schunk * 16;                                          \
      gl2lds16(src_, (char*)(LDSHALF) + j_ * 8192 + wave * 1024);                 \
    }                                                                             \
  }

// asm ds_read_b128: compiler emits NO waitcnt for these outputs — we own it.
#define READ_AF(DST, BUF, KH, MH)                                                 \
  _Pragma("unroll")                                                               \
  for (int i_ = 0; i_ < 4; ++i_)                                                  \
    asm volatile("ds_read_b128 %0, %1" : "=v"(DST[i_])                            \
        : "v"(ldsaddr(&As[BUF][KH][0] +                                           \
                      (waveM + ((MH) * 4 + i_) * 16 + l15) * 32 + rsw)));

#define READ_BF(DST, BUF, KH)                                                     \
  _Pragma("unroll")                                                               \
  for (int n_ = 0; n_ < 4; ++n_)                                                  \
    asm volatile("ds_read_b128 %0, %1" : "=v"(DST[n_])                            \
        : "v"(ldsaddr(&Bs[BUF][KH][0] + (waveN + n_ * 16 + l15) * 32 + rsw)));

// counted lgkm wait + full sched fence (rule #18)
#define LGKM4() { asm volatile("s_waitcnt lgkmcnt(4)"); __builtin_amdgcn_sched_barrier(0); }
#define LGKM8() { asm volatile("s_waitcnt lgkmcnt(8)"); __builtin_amdgcn_sched_barrier(0); }

#define MFMA16(AF, BF, MH)                                                        \
  __builtin_amdgcn_s_setprio(1);                                                  \
  _Pragma("unroll")                                                               \
  for (int i_ = 0; i_ < 4; ++i_)                                                  \
    _Pragma("unroll")                                                             \
    for (int n_ = 0; n_ < 4; ++n_)                                                \
      acc[(MH) * 4 + i_][n_] = __builtin_amdgcn_mfma_f32_16x16x32_bf16(           \
          AF[i_], BF[n_], acc[(MH) * 4 + i_][n_], 0, 0, 0);                       \
  __builtin_amdgcn_s_setprio(0);

#define SYNC2()                                                                   \
  asm volatile("s_waitcnt vmcnt(2)" ::: "memory");                                \
  asm volatile("s_barrier" ::: "memory");

  // KTILE(C, KTN): compute K-range held in buf C; stage k-offset KTN into buf 1-C.
#define KTILE(C, KTN)                                                             \
  { /* W0: read af1(C,kh0,mh1); stage A0'; wait W3prev reads; MFMA mh0 */         \
    READ_AF(af1, C, 0, 1)                                                         \
    STAGE(&As[1 - (C)][0][0], A, m0, (KTN) * 2)                                   \
    LGKM4()                                                                       \
    MFMA16(af0, bfvA, 0)                                                          \
    /* W1: sync; read af0(C,kh1,mh0)+bfvB(C,kh1); stage B0'; MFMA mh1 */          \
    SYNC2()                                                                       \
    READ_AF(af0, C, 1, 0)                                                         \
    READ_BF(bfvB, C, 1)                                                           \
    STAGE(&Bs[1 - (C)][0][0], B, n0, (KTN) * 2)                                   \
    LGKM8()                                                                       \
    MFMA16(af1, bfvA, 1)                                                          \
    /* W2: read af1(C,kh1,mh1); stage A1'; MFMA mh0 */                            \
    READ_AF(af1, C, 1, 1)                                                         \
    STAGE(&As[1 - (C)][1][0], A, m0, (KTN) * 2 + 64)                              \
    LGKM4()                                                                       \
    MFMA16(af0, bfvB, 0)                                                          \
    /* W3: sync; read next-tile af0+bfvA(1-C,kh0); stage B1'; MFMA mh1 */         \
    SYNC2()                                                                       \
    READ_AF(af0, 1 - (C), 0, 0)                                                   \
    READ_BF(bfvA, 1 - (C), 0)                                                     \
    STAGE(&Bs[1 - (C)][1][0], B, n0, (KTN) * 2 + 64)                              \
    LGKM8()                                                                       \
    MFMA16(af1, bfvB, 1)                                                          \
  }

  // prologue: stage tile0 into buf0, drain fully once, prime W0's operands.
  STAGE(&As[0][0][0], A, m0, 0);
  STAGE(&Bs[0][0][0], B, n0, 0);
  STAGE(&As[0][1][0], A, m0, 64);
  STAGE(&Bs[0][1][0], B, n0, 64);
  asm volatile("s_waitcnt vmcnt(0)" ::: "memory");
  asm volatile("s_barrier" ::: "memory");
  READ_AF(af0, 0, 0, 0)   // drained by first W0's LGKM4
  READ_BF(bfvA, 0, 0)

  for (int kt = 0; kt < GEMM_K; kt += 128) {
    KTILE(0, kt + 64)
    const int ktn1 = (kt + 128 < GEMM_K) ? (kt + 128) : 0;   // wrap: harmless restage
    KTILE(1, ktn1)
  }

#undef KTILE
#undef SYNC2
#undef MFMA16
#undef LGKM8
#undef LGKM4
#undef READ_BF
#undef READ_AF
#undef STAGE

  // epilogue: C/D layout col = lane&15, row = quad*4 + reg (proven m89/m91).
#pragma unroll
  for (int ni = 0; ni < 4; ++ni) {
    const int col = n0 + waveN + ni * 16 + l15;
    const float bv = bias[col];
#pragma unroll
    for (int mi = 0; mi < 8; ++mi) {
      const int row0 = m0 + waveM + mi * 16 + quad * 4;
#pragma unroll
      for (int r = 0; r < 4; ++r)
        out[(size_t)(row0 + r) * DOUT + col] = acc[mi][ni][r] + bv;
    }
  }
}

extern "C" void kernel_launch(void* const* d_in, const int* in_sizes, int n_in,
                              void* d_out, int out_size, void* d_ws, size_t ws_size,
                              hipStream_t stream) {
  const float* x    = (const float*)d_in[0];
  const float* c1   = (const float*)d_in[1];
  const float* c2   = (const float*)d_in[2];
  const float* bias = (const float*)d_in[3];
  float* out = (float*)d_out;

  // workspace layout (100 MB total)
  char* ws = (char*)d_ws;
  unsigned short* xb  = (unsigned short*)ws;                               // 67108864 B
  unsigned short* Wb  = (unsigned short*)(ws + 67108864);                  // 33554432 B
  unsigned short* c1b = (unsigned short*)(ws + 67108864 + 33554432);       //  2097152 B
  unsigned short* c2t = (unsigned short*)(ws + 67108864 + 33554432 + 2097152);  // 2097152 B

  k_f32_to_bf16<<<(TOKENS * DIN) / 2048, 256, 0, stream>>>(x, xb, TOKENS * DIN);
  k_f32_to_bf16<<<(64 * 64 * RANK) / 2048, 256, 0, stream>>>(c1, c1b, 64 * 64 * RANK);
  k_transpose_c2<<<dim3(64, 4), 256, 0, stream>>>(c2, c2t);

  // t-GEMM: [4096 x 256] @ [4096 x 256]^T -> W bf16 (permuted store), BK=32 (R1-proven)
  k_gemm_bt<RANK, 32, true><<<dim3(32, 32), 256, 0, stream>>>(c1b, c2t, nullptr, Wb, nullptr);
  // main GEMM: 256^2 pipeline with asm ds_read + counted lgkm
  k_gemm256<<<dim3(16, 32), 512, 0, stream>>>(xb, Wb, out, bias);
}